// Round 5
// baseline (1555.056 us; speedup 1.0000x reference)
//
#include <hip/hip_runtime.h>
#include <cstdint>
#include <cstddef>

// B=16, HW=4096, D=512, CL=768, K=512, V=512, NL=32, H=8.
// Inputs/outputs are FLOAT32. Internal big buffers bf16.
// Workspace ~201.5 MB; vis (bf16) hosted in d_out[0:64MB].

typedef __bf16 bf16x8 __attribute__((ext_vector_type(8)));
typedef float f32x4 __attribute__((ext_vector_type(4)));
typedef unsigned short ushort8 __attribute__((ext_vector_type(8)));

__device__ __forceinline__ float bf2f(unsigned short u) {
  union { unsigned int i; float f; } c; c.i = ((unsigned int)u) << 16; return c.f;
}
__device__ __forceinline__ unsigned short f2bf(float f) {
  union { float f; unsigned int i; } c; c.f = f;
  unsigned int r = c.i + 0x7FFFu + ((c.i >> 16) & 1u);
  return (unsigned short)(r >> 16);
}
__device__ __forceinline__ float gelu_f(float x) {
  return 0.5f * x * (1.f + erff(x * 0.70710678118654752f));
}

// ---------------- workspace layout (bytes) ----------------
constexpr size_t OFF_SRQ  = 0;                                   // f32 [16][512][2]
constexpr size_t OFF_SRLV = OFF_SRQ  + (size_t)16*512*2*4;       // f32 [16][768][2]
constexpr size_t OFF_SRW  = OFF_SRLV + (size_t)16*768*2*4;       // f32 [16][512][2]
constexpr size_t OFF_LACC = OFF_SRW  + (size_t)16*512*2*4;       // f32 [16][768][32]
constexpr size_t SZ_ZERO  = OFF_LACC + (size_t)16*768*32*4;      // zero [0, SZ_ZERO)
constexpr size_t OFF_STQ  = SZ_ZERO;                             // f32 [16][512][2]
constexpr size_t OFF_STLV = OFF_STQ  + (size_t)16*512*2*4;
constexpr size_t OFF_STW  = OFF_STLV + (size_t)16*768*2*4;
constexpr size_t OFF_KBUF = OFF_STW  + (size_t)16*512*2*4;       // f32 [16][512][32]
constexpr size_t OFF_VBUF = OFF_KBUF + (size_t)16*512*32*4;
constexpr size_t OFF_LANG = OFF_VBUF + (size_t)16*512*32*4;      // f32 [16][768][32]
constexpr size_t OFF_LMX  = OFF_LANG + (size_t)16*768*32*4;      // f32 [128][32]
constexpr size_t OFF_LSM  = OFF_LMX  + (size_t)128*32*4;
constexpr size_t OFF_LNORM= OFF_LSM  + (size_t)128*32*4;         // f32 [16][768][32]
constexpr size_t OFF_P2   = OFF_LNORM+ (size_t)16*768*32*4;      // f32 [16][768][32]
constexpr size_t OFF_PMX  = OFF_P2   + (size_t)16*768*32*4;      // f32 [32][128][32] partial max
constexpr size_t OFF_PSM  = OFF_PMX  + (size_t)32*128*32*4;      // f32 [32][128][32] partial sum
constexpr size_t OFF_Q    = OFF_PSM  + (size_t)32*128*32*4;      // bf16 q; reused: att@v out, then P
constexpr size_t OFF_LV   = OFF_Q    + (size_t)65536*512*2;      // bf16 lv; Wraw overlays after langout
constexpr size_t OFF_SIMB = OFF_LV   + (size_t)65536*768*2;      // bf16 sim (B,H,4096,32)
// total ≈ 211.3 MB

// ---------------- big GEMM: Y[m,n] = sum_k A[m,k]*W[n,k] + b[n] ----------------
template<bool AF32, bool GELU, bool STATS, bool OUTF32>
__global__ __launch_bounds__(256) void gemm_bt(
    const void* __restrict__ Ain, const float* __restrict__ W,
    const float* __restrict__ bias, void* __restrict__ Yout,
    float* __restrict__ statsraw, int N, int Kd)
{
  __shared__ __align__(16) unsigned short As[128 * 64];
  __shared__ __align__(16) unsigned short Bs[128 * 64];
  const int t = threadIdx.x;
  const int wave = t >> 6, lane = t & 63;
  const int ln = lane & 15, quad = lane >> 4;
  const int m0 = blockIdx.x * 128, n0 = blockIdx.y * 128;
  const int wm = (wave >> 1) * 64, wn = (wave & 1) * 64;
  const f32x4 fzero = {0.f, 0.f, 0.f, 0.f};
  f32x4 acc[4][4];
#pragma unroll
  for (int i = 0; i < 4; ++i)
#pragma unroll
    for (int j = 0; j < 4; ++j) acc[i][j] = fzero;
  const int lrow = t >> 3;      // 0..31
  const int lch  = t & 7;       // 8-elem chunk index within 64-k slice

  for (int k0 = 0; k0 < Kd; k0 += 64) {
    ushort8 ar[4], br[4];
#pragma unroll
    for (int i = 0; i < 4; ++i) {
      int row = i * 32 + lrow;
      const float* wp = W + (size_t)(n0 + row) * Kd + k0 + lch * 8;
      f32x4 w0 = *(const f32x4*)wp, w1 = *(const f32x4*)(wp + 4);
#pragma unroll
      for (int j = 0; j < 4; ++j) { br[i][j] = f2bf(w0[j]); br[i][j + 4] = f2bf(w1[j]); }
      if (AF32) {
        const float* ap = (const float*)Ain + (size_t)(m0 + row) * Kd + k0 + lch * 8;
        f32x4 a0 = *(const f32x4*)ap, a1 = *(const f32x4*)(ap + 4);
#pragma unroll
        for (int j = 0; j < 4; ++j) { ar[i][j] = f2bf(a0[j]); ar[i][j + 4] = f2bf(a1[j]); }
      } else {
        ar[i] = *(const ushort8*)((const unsigned short*)Ain +
                                  (size_t)(m0 + row) * Kd + k0 + lch * 8);
      }
    }
    __syncthreads();
#pragma unroll
    for (int i = 0; i < 4; ++i) {
      int row = i * 32 + lrow;
      *(ushort8*)&As[row * 64 + lch * 8] = ar[i];
      *(ushort8*)&Bs[row * 64 + lch * 8] = br[i];
    }
    __syncthreads();
#pragma unroll
    for (int kk = 0; kk < 64; kk += 32) {
      int c = (kk >> 3) + quad;
      bf16x8 af[4], bfr[4];
#pragma unroll
      for (int i = 0; i < 4; ++i)
        af[i] = *(const bf16x8*)&As[(wm + i * 16 + ln) * 64 + c * 8];
#pragma unroll
      for (int j = 0; j < 4; ++j)
        bfr[j] = *(const bf16x8*)&Bs[(wn + j * 16 + ln) * 64 + c * 8];
#pragma unroll
      for (int i = 0; i < 4; ++i)
#pragma unroll
        for (int j = 0; j < 4; ++j)
          acc[i][j] = __builtin_amdgcn_mfma_f32_16x16x32_bf16(af[i], bfr[j], acc[i][j], 0, 0, 0);
    }
  }
  __syncthreads();
  float bb[4];
#pragma unroll
  for (int j = 0; j < 4; ++j) bb[j] = bias[n0 + wn + j * 16 + ln];
#pragma unroll
  for (int i = 0; i < 4; ++i)
#pragma unroll
    for (int j = 0; j < 4; ++j)
#pragma unroll
      for (int r = 0; r < 4; ++r) {
        float v = acc[i][j][r] + bb[j];
        if (GELU) v = gelu_f(v);
        acc[i][j][r] = v;
        size_t row = (size_t)(m0 + wm + i * 16 + quad * 4 + r);
        size_t idx = row * N + (n0 + wn + j * 16 + ln);
        if (OUTF32) ((float*)Yout)[idx] = v;
        else ((unsigned short*)Yout)[idx] = f2bf(v);
      }
  if (STATS) {
    float* cs = (float*)As;  // 256 floats: [0..127]=sum, [128..255]=sumsq
    cs[t] = 0.f;
    __syncthreads();
#pragma unroll
    for (int j = 0; j < 4; ++j) {
      float s = 0.f, s2 = 0.f;
#pragma unroll
      for (int i = 0; i < 4; ++i)
#pragma unroll
        for (int r = 0; r < 4; ++r) { float v = acc[i][j][r]; s += v; s2 += v * v; }
      int cl = wn + j * 16 + ln;
      atomicAdd(&cs[cl], s);
      atomicAdd(&cs[128 + cl], s2);
    }
    __syncthreads();
    int bIdx = m0 >> 12;
    if (t < 128) atomicAdd(&statsraw[((size_t)bIdx * N + n0 + t) * 2], cs[t]);
    else atomicAdd(&statsraw[((size_t)bIdx * N + n0 + (t - 128)) * 2 + 1], cs[t]);
  }
}

__global__ void finalize_stats(const float* __restrict__ raw, float* __restrict__ st,
                               int n, float invc) {
  int i = blockIdx.x * 256 + threadIdx.x;
  if (i >= n) return;
  float s = raw[2 * i], s2 = raw[2 * i + 1];
  float m = s * invc;
  float v = fmaxf(s2 * invc - m * m, 0.f);
  st[2 * i] = m;
  st[2 * i + 1] = rsqrtf(v + 1e-5f);
}

// ---------------- small conv over NL=32 (all f32) ----------------
template<int EPI>   // 0: *mask   1: gelu
__global__ __launch_bounds__(256) void sconv(
    const float* __restrict__ l, const float* __restrict__ w,
    const float* __restrict__ bias, const float* __restrict__ lmask,
    float* __restrict__ out, int O, int Cin)
{
  int b = blockIdx.x, og = blockIdx.y;
  int ol = threadIdx.x >> 5, n = threadIdx.x & 31;
  int o = og * 8 + ol;
  const float* lb = l + (size_t)b * Cin * 32 + n;
  const float* wr = w + (size_t)o * Cin;
  float s = 0.f;
#pragma unroll 4
  for (int i = 0; i < Cin; ++i) s += wr[i] * lb[(size_t)i * 32];
  s += bias[o];
  if (EPI == 0) s *= lmask[b * 32 + n];
  else s = gelu_f(s);
  out[((size_t)b * O + o) * 32 + n] = s;
}

// ---------------- fused sim + att-softmax + att@v + latt partial stats ----------------
__global__ __launch_bounds__(256) void simattv_kernel(
    const unsigned short* __restrict__ qraw, const float* __restrict__ stq,
    const float* __restrict__ kbuf, const float* __restrict__ vbuf,
    const float* __restrict__ lmask,
    unsigned short* __restrict__ simb, unsigned short* __restrict__ outb,
    float* __restrict__ pmx, float* __restrict__ psm)
{
  __shared__ __align__(16) float qs[128][68];
  __shared__ __align__(16) float ks[64][36];
  __shared__ __align__(16) float vs[64][36];
  __shared__ __align__(16) float ss[128][36];
  __shared__ float sm[64], sr[64], mb[32];
  __shared__ float gm[8][32], gs[8][32];
  int qc = blockIdx.x, q0 = qc * 128, h = blockIdx.y, b = blockIdx.z;
  int bh = b * 8 + h;
  int t = threadIdx.x;
  if (t < 64) {
    sm[t] = stq[(b * 512 + h * 64 + t) * 2];
    sr[t] = stq[(b * 512 + h * 64 + t) * 2 + 1];
  } else if (t < 96) {
    mb[t - 64] = 10000.f * (lmask[b * 32 + (t - 64)] - 1.f);
  }
  for (int e = t; e < 2048; e += 256) {
    int d = e >> 5, n = e & 31;
    ks[d][n] = kbuf[((size_t)b * 512 + h * 64 + d) * 32 + n];
    vs[d][n] = vbuf[((size_t)b * 512 + h * 64 + d) * 32 + n];
  }
  __syncthreads();
  const float scale = 0.04419417382415922f;  // 512^-0.5
  for (int e = t; e < 8192; e += 256) {
    int ql = e >> 6, d = e & 63;
    float v = bf2f(qraw[((size_t)(b * 4096) + q0 + ql) * 512 + h * 64 + d]);
    qs[ql][d] = (v - sm[d]) * sr[d] * scale;
  }
  __syncthreads();
  int ql = t >> 1, half = t & 1, nb = half * 16;
  float acc[16];
#pragma unroll
  for (int i = 0; i < 16; ++i) acc[i] = 0.f;
  for (int d = 0; d < 64; ++d) {
    float qv = qs[ql][d];
    const f32x4* kp = (const f32x4*)&ks[d][nb];
#pragma unroll
    for (int u = 0; u < 4; ++u) {
      f32x4 kv = kp[u];
      acc[u * 4 + 0] += qv * kv[0]; acc[u * 4 + 1] += qv * kv[1];
      acc[u * 4 + 2] += qv * kv[2]; acc[u * 4 + 3] += qv * kv[3];
    }
  }
  unsigned short* sg = simb + (((size_t)bh) * 4096 + q0 + ql) * 32 + nb;
#pragma unroll
  for (int i = 0; i < 16; ++i) {
    float v = acc[i] + mb[nb + i];
    ss[ql][nb + i] = v;
    sg[i] = f2bf(v);
  }
  __syncthreads();
  // ---- latt partial stats over this block's 128 q rows, per n column ----
  {
    int n2 = t & 31, rg = t >> 5;   // 8 row-groups of 16 rows
    float pm = -1e30f;
#pragma unroll
    for (int r = 0; r < 16; ++r) pm = fmaxf(pm, ss[rg * 16 + r][n2]);
    float psv = 0.f;
#pragma unroll
    for (int r = 0; r < 16; ++r) psv += __expf(ss[rg * 16 + r][n2] - pm);
    gm[rg][n2] = pm; gs[rg][n2] = psv;
  }
  __syncthreads();
  if (t < 32) {
    float M = gm[0][t], S = gs[0][t];
#pragma unroll
    for (int g = 1; g < 8; ++g) {
      float m2 = gm[g][t], s2 = gs[g][t];
      if (m2 > M) { S = S * __expf(M - m2) + s2; M = m2; }
      else S += s2 * __expf(m2 - M);
    }
    pmx[((size_t)qc * 128 + bh) * 32 + t] = M;
    psm[((size_t)qc * 128 + bh) * 32 + t] = S;
  }
  __syncthreads();
  // ---- att softmax over n (32) per q row ----
  float xv[16];
  float mx = -1e30f;
#pragma unroll
  for (int i = 0; i < 16; ++i) { xv[i] = ss[ql][nb + i]; mx = fmaxf(mx, xv[i]); }
  mx = fmaxf(mx, __shfl_xor(mx, 1));
  float s = 0.f;
#pragma unroll
  for (int i = 0; i < 16; ++i) { xv[i] = __expf(xv[i] - mx); s += xv[i]; }
  s += __shfl_xor(s, 1);
  float inv = 1.f / s;
#pragma unroll
  for (int i = 0; i < 16; ++i) ss[ql][nb + i] = xv[i] * inv;
  __syncthreads();
  float pr[32];
#pragma unroll
  for (int i = 0; i < 8; ++i) ((f32x4*)pr)[i] = ((const f32x4*)&ss[ql][0])[i];
  unsigned short* op = outb + ((size_t)b * 4096 + q0 + ql) * 512 + h * 64 + half * 32;
#pragma unroll
  for (int d = 0; d < 32; ++d) {
    const float* vr = &vs[half * 32 + d][0];
    float a = 0.f;
#pragma unroll
    for (int n4 = 0; n4 < 8; ++n4) {
      f32x4 v4 = *(const f32x4*)&vr[n4 * 4];
      a += pr[n4 * 4 + 0] * v4[0] + pr[n4 * 4 + 1] * v4[1] +
           pr[n4 * 4 + 2] * v4[2] + pr[n4 * 4 + 3] * v4[3];
    }
    op[d] = f2bf(a);
  }
}

// ---------------- merge latt partial stats: 32 q-chunks -> final (lmx,lsm) ----------------
__global__ __launch_bounds__(256) void latt_merge(const float* __restrict__ pmx,
                                                  const float* __restrict__ psm,
                                                  float* __restrict__ lmx,
                                                  float* __restrict__ lsm)
{
  int i = blockIdx.x * 256 + threadIdx.x;   // 0..4095 = bh*32+n
  int bh = i >> 5, n = i & 31;
  float M = -1e30f, S = 0.f;
#pragma unroll 4
  for (int c = 0; c < 32; ++c) {
    float m2 = pmx[((size_t)c * 128 + bh) * 32 + n];
    float s2 = psm[((size_t)c * 128 + bh) * 32 + n];
    if (m2 > M) { S = S * __expf(M - m2) + s2; M = m2; }
    else S += s2 * __expf(m2 - M);
  }
  lmx[bh * 32 + n] = M;
  lsm[bh * 32 + n] = S;
}

// ---------------- lang_out[b,h,c,n] += sum_q latt[n,q]*lvnorm[c,q] ----------------
__global__ __launch_bounds__(256) void langout_acc_kernel(
    const unsigned short* __restrict__ simb, const float* __restrict__ lmx,
    const float* __restrict__ lsm, const unsigned short* __restrict__ lvraw,
    const float* __restrict__ stlv, float* __restrict__ lacc)
{
  __shared__ __align__(16) float pt[64][32];
  __shared__ __align__(16) float lvt[64][96];
  __shared__ float cm[96], cr[96], lm[32], li[32];
  int bh = blockIdx.x, b = bh >> 3, h = bh & 7;
  int qs0 = blockIdx.y * 512;
  int t = threadIdx.x;
  if (t < 96) { cm[t] = stlv[(b * 768 + h * 96 + t) * 2]; cr[t] = stlv[(b * 768 + h * 96 + t) * 2 + 1]; }
  else if (t >= 128 && t < 160) {
    int n = t - 128;
    lm[n] = lmx[bh * 32 + n];
    li[n] = 1.f / lsm[bh * 32 + n];
  }
  __syncthreads();
  int n = t & 31, cg = t >> 5;
  float acc[12];
#pragma unroll
  for (int r = 0; r < 12; ++r) acc[r] = 0.f;
  for (int c0 = 0; c0 < 512; c0 += 64) {
    if (c0) __syncthreads();
#pragma unroll
    for (int i = 0; i < 8; ++i) {
      int e = t + 256 * i;
      int ql = e >> 5, nn = e & 31;
      float x = bf2f(simb[((size_t)bh * 4096 + qs0 + c0 + ql) * 32 + nn]);
      pt[ql][nn] = __expf(x - lm[nn]) * li[nn];
    }
#pragma unroll
    for (int i = 0; i < 24; ++i) {
      int e = t + 256 * i;
      int ql = e / 96, cc = e % 96;
      float v = bf2f(lvraw[((size_t)(b * 4096) + qs0 + c0 + ql) * 768 + h * 96 + cc]);
      lvt[ql][cc] = (v - cm[cc]) * cr[cc];
    }
    __syncthreads();
    for (int q = 0; q < 64; ++q) {
      float pv = pt[q][n];
      const f32x4* lp = (const f32x4*)&lvt[q][cg * 12];
      f32x4 a0 = lp[0], a1 = lp[1], a2 = lp[2];
      acc[0] += pv * a0[0]; acc[1] += pv * a0[1]; acc[2]  += pv * a0[2]; acc[3]  += pv * a0[3];
      acc[4] += pv * a1[0]; acc[5] += pv * a1[1]; acc[6]  += pv * a1[2]; acc[7]  += pv * a1[3];
      acc[8] += pv * a2[0]; acc[9] += pv * a2[1]; acc[10] += pv * a2[2]; acc[11] += pv * a2[3];
    }
  }
#pragma unroll
  for (int r = 0; r < 12; ++r)
    atomicAdd(&lacc[((size_t)b * 768 + h * 96 + cg * 12 + r) * 32 + n], acc[r]);
}

// ---------------- P = vis * inorm(Wout) ----------------
__global__ __launch_bounds__(256) void prod_kernel(
    const unsigned short* __restrict__ visb, const unsigned short* __restrict__ wraw,
    const float* __restrict__ stw, unsigned short* __restrict__ P)
{
  size_t idx = ((size_t)blockIdx.x * 256 + threadIdx.x) * 8;
  int b = (int)(idx >> 21);
  int c = (int)(idx & 511);
  ushort8 vv = *(const ushort8*)&visb[idx];
  ushort8 wv = *(const ushort8*)&wraw[idx];
  ushort8 pv;
#pragma unroll
  for (int i = 0; i < 8; ++i) {
    float mean = stw[(b * 512 + c + i) * 2], rs = stw[(b * 512 + c + i) * 2 + 1];
    pv[i] = f2bf(bf2f(vv[i]) * ((bf2f(wv[i]) - mean) * rs));
  }
  *(ushort8*)&P[idx] = pv;
}

// ---------------- langW conv + inorm over NL (f32) ----------------
__global__ __launch_bounds__(256) void langW_kernel(
    const float* __restrict__ lacc, const float* __restrict__ w,
    const float* __restrict__ bias, const float* __restrict__ lmask,
    float* __restrict__ lnorm)
{
  int b = blockIdx.x, og = blockIdx.y;
  int ol = threadIdx.x >> 5, n = threadIdx.x & 31;
  int o = og * 8 + ol;
  const float* ab = lacc + (size_t)b * 768 * 32 + n;
  const float* wr = w + (size_t)o * 768;
  float s = 0.f;
#pragma unroll 4
  for (int i = 0; i < 768; ++i) s += wr[i] * ab[(size_t)i * 32];
  float y = s * lmask[b * 32 + n] + bias[o];
  float m = y;
#pragma unroll
  for (int off = 16; off >= 1; off >>= 1) m += __shfl_xor(m, off);
  m *= (1.f / 32.f);
  float d = y - m;
  float vv = d * d;
#pragma unroll
  for (int off = 16; off >= 1; off >>= 1) vv += __shfl_xor(vv, off);
  vv *= (1.f / 32.f);
  lnorm[((size_t)b * 768 + o) * 32 + n] = d * rsqrtf(vv + 1e-5f);
}

__global__ __launch_bounds__(256) void p2_kernel(const float* __restrict__ a,
                                                 const float* __restrict__ b,
                                                 float* __restrict__ o, int n) {
  int i = blockIdx.x * 256 + threadIdx.x;
  if (i < n) o[i] = a[i] * b[i];
}

// ---------------- langmm conv + gelu, store transposed (B,NL,CL) f32 ----------------
__global__ __launch_bounds__(256) void langmm_kernel(
    const float* __restrict__ p2, const float* __restrict__ w,
    const float* __restrict__ bias, float* __restrict__ out1)
{
  int b = blockIdx.x, og = blockIdx.y;
  int ol = threadIdx.x >> 5, n = threadIdx.x & 31;
  int o = og * 8 + ol;
  const float* pb = p2 + (size_t)b * 768 * 32 + n;
  const float* wr = w + (size_t)o * 768;
  float s = 0.f;
#pragma unroll 4
  for (int i = 0; i < 768; ++i) s += wr[i] * pb[(size_t)i * 32];
  s = gelu_f(s + bias[o]);
  __shared__ float tile[8][32];
  tile[ol][n] = s;
  __syncthreads();
  int nn = threadIdx.x >> 3, cl = threadIdx.x & 7;
  out1[((size_t)b * 32 + nn) * 768 + og * 8 + cl] = tile[cl][nn];
}

// ---------------- launch ----------------
extern "C" void kernel_launch(void* const* d_in, const int* in_sizes, int n_in,
                              void* d_out, int out_size, void* d_ws, size_t ws_size,
                              hipStream_t stream)
{
  (void)in_sizes; (void)n_in; (void)out_size; (void)ws_size;
  const float* x       = (const float*)d_in[0];
  const float* l       = (const float*)d_in[1];
  const float* lmask   = (const float*)d_in[2];
  const float* w_vis   = (const float*)d_in[3];
  const float* b_vis   = (const float*)d_in[4];
  const float* w_langp = (const float*)d_in[5];
  const float* b_langp = (const float*)d_in[6];
  const float* w_q     = (const float*)d_in[7];
  const float* b_q     = (const float*)d_in[8];
  const float* w_k     = (const float*)d_in[9];
  const float* b_k     = (const float*)d_in[10];
  const float* w_v     = (const float*)d_in[11];
  const float* b_v     = (const float*)d_in[12];
  const float* w_lv    = (const float*)d_in[13];
  const float* b_lv    = (const float*)d_in[14];
  const float* w_W     = (const float*)d_in[15];
  const float* b_W     = (const float*)d_in[16];
  const float* w_langW = (const float*)d_in[17];
  const float* b_langW = (const float*)d_in[18];
  const float* w_mm    = (const float*)d_in[19];
  const float* b_mm    = (const float*)d_in[20];
  const float* w_langmm= (const float*)d_in[21];
  const float* b_langmm= (const float*)d_in[22];

  char* ws = (char*)d_ws;
  float* srq  = (float*)(ws + OFF_SRQ);
  float* srlv = (float*)(ws + OFF_SRLV);
  float* srw  = (float*)(ws + OFF_SRW);
  float* lacc = (float*)(ws + OFF_LACC);
  float* stq  = (float*)(ws + OFF_STQ);
  float* stlv = (float*)(ws + OFF_STLV);
  float* stw  = (float*)(ws + OFF_STW);
  float* kbuf = (float*)(ws + OFF_KBUF);
  float* vbuf = (float*)(ws + OFF_VBUF);
  float* lang = (float*)(ws + OFF_LANG);
  float* lmx  = (float*)(ws + OFF_LMX);
  float* lsm  = (float*)(ws + OFF_LSM);
  float* lnorm= (float*)(ws + OFF_LNORM);
  float* p2   = (float*)(ws + OFF_P2);
  float* pmx  = (float*)(ws + OFF_PMX);
  float* psm  = (float*)(ws + OFF_PSM);
  unsigned short* qraw  = (unsigned short*)(ws + OFF_Q);
  unsigned short* lvraw = (unsigned short*)(ws + OFF_LV);
  unsigned short* wraw  = (unsigned short*)(ws + OFF_LV);
  unsigned short* simb  = (unsigned short*)(ws + OFF_SIMB);
  float* out0 = (float*)d_out;
  float* out1 = out0 + (size_t)16 * 4096 * 512;
  unsigned short* visb = (unsigned short*)d_out;

  hipMemsetAsync(ws, 0, SZ_ZERO, stream);

  // language-side small convs (f32)
  sconv<1><<<dim3(16, 96), 256, 0, stream>>>(l, w_langp, b_langp, lmask, lang, 768, 768);
  sconv<0><<<dim3(16, 64), 256, 0, stream>>>(l, w_k, b_k, lmask, kbuf, 512, 768);
  sconv<0><<<dim3(16, 64), 256, 0, stream>>>(l, w_v, b_v, lmask, vbuf, 512, 768);

  // big GEMMs on x (f32 A, f32 W -> bf16 out)
  gemm_bt<true, true,  false, false><<<dim3(512, 4), 256, 0, stream>>>(x, w_vis, b_vis, visb, nullptr, 512, 512);
  gemm_bt<true, false, true,  false><<<dim3(512, 4), 256, 0, stream>>>(x, w_q,   b_q,   qraw,  srq,   512, 512);
  gemm_bt<true, false, true,  false><<<dim3(512, 6), 256, 0, stream>>>(x, w_lv,  b_lv,  lvraw, srlv,  768, 512);
  finalize_stats<<<32, 256, 0, stream>>>(srq,  stq,  16 * 512, 1.f / 4096.f);
  finalize_stats<<<48, 256, 0, stream>>>(srlv, stlv, 16 * 768, 1.f / 4096.f);

  // attention (fused sim+softmax+PV+latt partials)
  simattv_kernel<<<dim3(32, 8, 16), 256, 0, stream>>>(qraw, stq, kbuf, vbuf, lmask, simb, qraw, pmx, psm);
  latt_merge<<<16, 256, 0, stream>>>(pmx, psm, lmx, lsm);
  langout_acc_kernel<<<dim3(128, 8), 256, 0, stream>>>(simb, lmx, lsm, lvraw, stlv, lacc);

  // visual output path
  gemm_bt<false, false, true,  false><<<dim3(512, 4), 256, 0, stream>>>(qraw, w_W, b_W, wraw, srw, 512, 512);
  finalize_stats<<<32, 256, 0, stream>>>(srw, stw, 16 * 512, 1.f / 4096.f);
  prod_kernel<<<16384, 256, 0, stream>>>(visb, wraw, stw, qraw);
  gemm_bt<false, true,  false, true ><<<dim3(512, 4), 256, 0, stream>>>(qraw, w_mm, b_mm, out0, nullptr, 512, 512);

  // language output path
  langW_kernel<<<dim3(16, 96), 256, 0, stream>>>(lacc, w_langW, b_langW, lmask, lnorm);
  p2_kernel<<<1536, 256, 0, stream>>>(lang, lnorm, p2, 16 * 768 * 32);
  langmm_kernel<<<dim3(16, 96), 256, 0, stream>>>(p2, w_langmm, b_langmm, out1);
}

// Round 6
// 1379.574 us; speedup vs baseline: 1.1272x; 1.1272x over previous
//
#include <hip/hip_runtime.h>
#include <cstdint>
#include <cstddef>

// B=16, HW=4096, D=512, CL=768, K=512, V=512, NL=32, H=8.
// I/O FLOAT32. Internal big buffers bf16. ws ~214 MB.
// d_out hosting: [0,64MB)=visb bf16, [64,128MB)=xb bf16; both dead before mm GEMM writes f32.

typedef __bf16 bf16x8 __attribute__((ext_vector_type(8)));
typedef float f32x4 __attribute__((ext_vector_type(4)));
typedef unsigned short ushort8 __attribute__((ext_vector_type(8)));

__device__ __forceinline__ float bf2f(unsigned short u) {
  union { unsigned int i; float f; } c; c.i = ((unsigned int)u) << 16; return c.f;
}
__device__ __forceinline__ unsigned short f2bf(float f) {
  union { float f; unsigned int i; } c; c.f = f;
  unsigned int r = c.i + 0x7FFFu + ((c.i >> 16) & 1u);
  return (unsigned short)(r >> 16);
}
__device__ __forceinline__ float gelu_f(float x) {
  return 0.5f * x * (1.f + erff(x * 0.70710678118654752f));
}
__device__ __forceinline__ void gload16(const void* g, void* l) {
  __builtin_amdgcn_global_load_lds(
      (__attribute__((address_space(1))) unsigned int*)g,
      (__attribute__((address_space(3))) unsigned int*)l, 16, 0, 0);
}

// ---------------- workspace layout (bytes) ----------------
constexpr size_t OFF_SRQ  = 0;                                   // f32 [16][512][2]
constexpr size_t OFF_SRLV = OFF_SRQ  + (size_t)16*512*2*4;       // f32 [16][768][2]
constexpr size_t OFF_SRW  = OFF_SRLV + (size_t)16*768*2*4;       // f32 [16][512][2]
constexpr size_t OFF_LACC = OFF_SRW  + (size_t)16*512*2*4;       // f32 [16][768][32]
constexpr size_t SZ_ZERO  = OFF_LACC + (size_t)16*768*32*4;      // zero [0, SZ_ZERO)
constexpr size_t OFF_STQ  = SZ_ZERO;                             // f32 [16][512][2]
constexpr size_t OFF_STLV = OFF_STQ  + (size_t)16*512*2*4;
constexpr size_t OFF_STW  = OFF_STLV + (size_t)16*768*2*4;
constexpr size_t OFF_KBUF = OFF_STW  + (size_t)16*512*2*4;       // f32 [16][512][32]
constexpr size_t OFF_VBUF = OFF_KBUF + (size_t)16*512*32*4;
constexpr size_t OFF_LANG = OFF_VBUF + (size_t)16*512*32*4;      // f32 [16][768][32]
constexpr size_t OFF_LMX  = OFF_LANG + (size_t)16*768*32*4;      // f32 [128][32]
constexpr size_t OFF_LSM  = OFF_LMX  + (size_t)128*32*4;
constexpr size_t OFF_LNORM= OFF_LSM  + (size_t)128*32*4;         // f32 [16][768][32]
constexpr size_t OFF_P2   = OFF_LNORM+ (size_t)16*768*32*4;      // f32 [16][768][32]
constexpr size_t OFF_PMX  = OFF_P2   + (size_t)16*768*32*4;      // f32 [32][128][32]
constexpr size_t OFF_PSM  = OFF_PMX  + (size_t)32*128*32*4;      // f32 [32][128][32]
constexpr size_t OFF_WB   = OFF_PSM  + (size_t)32*128*32*4;      // bf16 weights: vis,q,lv,W,mm
constexpr size_t OFF_Q    = OFF_WB   + (size_t)1441792*2;        // bf16 q; reused: att@v out, then P
constexpr size_t OFF_LV   = OFF_Q    + (size_t)65536*512*2;      // bf16 lv; Wraw overlays after langout
constexpr size_t OFF_SIMB = OFF_LV   + (size_t)65536*768*2;      // bf16 sim (B,H,4096,32)
// total ≈ 214.2 MB

// ---------------- f32 -> bf16 convert (x and weights) ----------------
__global__ __launch_bounds__(256) void cvt_bf16(const float* __restrict__ src,
                                                unsigned short* __restrict__ dst, int n8)
{
  int i = blockIdx.x * 256 + threadIdx.x;
  if (i >= n8) return;
  const f32x4* s = (const f32x4*)(src + (size_t)i * 8);
  f32x4 a = s[0], b = s[1];
  ushort8 o;
#pragma unroll
  for (int j = 0; j < 4; ++j) { o[j] = f2bf(a[j]); o[j + 4] = f2bf(b[j]); }
  *(ushort8*)(dst + (size_t)i * 8) = o;
}

// ---------------- big GEMM (m97 pattern): Y[m,n] = sum_k A[m,k]*Wb[n,k] + b[n] ----------------
// A, Wb bf16. 128x128 tile, 4 waves, global_load_lds width-16 staging, 2-barrier K-loop.
template<bool GELU, bool STATS, bool OUTF32>
__global__ __launch_bounds__(256) void gemm_bt(
    const unsigned short* __restrict__ A, const unsigned short* __restrict__ Wb,
    const float* __restrict__ bias, void* __restrict__ Yout,
    float* __restrict__ statsraw, int N, int Kd)
{
  __shared__ __align__(16) unsigned short As[128 * 64];
  __shared__ __align__(16) unsigned short Bs[128 * 64];
  const int t = threadIdx.x;
  const int wave = t >> 6, lane = t & 63;
  const int ln = lane & 15, quad = lane >> 4;
  const int m0 = blockIdx.x * 128, n0 = blockIdx.y * 128;
  const int wm = (wave >> 1) * 64, wn = (wave & 1) * 64;
  const f32x4 fzero = {0.f, 0.f, 0.f, 0.f};
  f32x4 acc[4][4];
#pragma unroll
  for (int i = 0; i < 4; ++i)
#pragma unroll
    for (int j = 0; j < 4; ++j) acc[i][j] = fzero;
  const int lrow = lane >> 3;   // 0..7
  const int lch  = lane & 7;    // 8-elem chunk

  for (int k0 = 0; k0 < Kd; k0 += 64) {
#pragma unroll
    for (int it = 0; it < 4; ++it) {
      int g = wave * 4 + it;                 // 16 groups of 8 rows
      int row = g * 8 + lrow;
      gload16(A  + (size_t)(m0 + row) * Kd + k0 + lch * 8, &As[g * 512]);
      gload16(Wb + (size_t)(n0 + row) * Kd + k0 + lch * 8, &Bs[g * 512]);
    }
    __syncthreads();   // drains vmcnt (global_load_lds) before any LDS read
#pragma unroll
    for (int kk = 0; kk < 64; kk += 32) {
      int c = (kk >> 3) + quad;
      bf16x8 af[4], bfr[4];
#pragma unroll
      for (int i = 0; i < 4; ++i)
        af[i] = *(const bf16x8*)&As[(wm + i * 16 + ln) * 64 + c * 8];
#pragma unroll
      for (int j = 0; j < 4; ++j)
        bfr[j] = *(const bf16x8*)&Bs[(wn + j * 16 + ln) * 64 + c * 8];
#pragma unroll
      for (int i = 0; i < 4; ++i)
#pragma unroll
        for (int j = 0; j < 4; ++j)
          acc[i][j] = __builtin_amdgcn_mfma_f32_16x16x32_bf16(af[i], bfr[j], acc[i][j], 0, 0, 0);
    }
    __syncthreads();
  }
  float bb[4];
#pragma unroll
  for (int j = 0; j < 4; ++j) bb[j] = bias[n0 + wn + j * 16 + ln];
#pragma unroll
  for (int i = 0; i < 4; ++i)
#pragma unroll
    for (int j = 0; j < 4; ++j)
#pragma unroll
      for (int r = 0; r < 4; ++r) {
        float v = acc[i][j][r] + bb[j];
        if (GELU) v = gelu_f(v);
        acc[i][j][r] = v;
        size_t row = (size_t)(m0 + wm + i * 16 + quad * 4 + r);
        size_t idx = row * N + (n0 + wn + j * 16 + ln);
        if (OUTF32) ((float*)Yout)[idx] = v;
        else ((unsigned short*)Yout)[idx] = f2bf(v);
      }
  if (STATS) {
    float* cs = (float*)As;  // 256 floats: [0..127]=sum, [128..255]=sumsq
    cs[t] = 0.f;
    __syncthreads();
#pragma unroll
    for (int j = 0; j < 4; ++j) {
      float s = 0.f, s2 = 0.f;
#pragma unroll
      for (int i = 0; i < 4; ++i)
#pragma unroll
        for (int r = 0; r < 4; ++r) { float v = acc[i][j][r]; s += v; s2 += v * v; }
      int cl = wn + j * 16 + ln;
      atomicAdd(&cs[cl], s);
      atomicAdd(&cs[128 + cl], s2);
    }
    __syncthreads();
    int bIdx = m0 >> 12;
    if (t < 128) atomicAdd(&statsraw[((size_t)bIdx * N + n0 + t) * 2], cs[t]);
    else atomicAdd(&statsraw[((size_t)bIdx * N + n0 + (t - 128)) * 2 + 1], cs[t]);
  }
}

__global__ void finalize_stats(const float* __restrict__ raw, float* __restrict__ st,
                               int n, float invc) {
  int i = blockIdx.x * 256 + threadIdx.x;
  if (i >= n) return;
  float s = raw[2 * i], s2 = raw[2 * i + 1];
  float m = s * invc;
  float v = fmaxf(s2 * invc - m * m, 0.f);
  st[2 * i] = m;
  st[2 * i + 1] = rsqrtf(v + 1e-5f);
}

// ---------------- small conv over NL=32 (all f32) ----------------
template<int EPI>   // 0: *mask   1: gelu
__global__ __launch_bounds__(256) void sconv(
    const float* __restrict__ l, const float* __restrict__ w,
    const float* __restrict__ bias, const float* __restrict__ lmask,
    float* __restrict__ out, int O, int Cin)
{
  int b = blockIdx.x, og = blockIdx.y;
  int ol = threadIdx.x >> 5, n = threadIdx.x & 31;
  int o = og * 8 + ol;
  const float* lb = l + (size_t)b * Cin * 32 + n;
  const float* wr = w + (size_t)o * Cin;
  float s = 0.f;
#pragma unroll 4
  for (int i = 0; i < Cin; ++i) s += wr[i] * lb[(size_t)i * 32];
  s += bias[o];
  if (EPI == 0) s *= lmask[b * 32 + n];
  else s = gelu_f(s);
  out[((size_t)b * O + o) * 32 + n] = s;
}

// ---------------- fused sim + att-softmax + att@v + latt partial stats ----------------
__global__ __launch_bounds__(256) void simattv_kernel(
    const unsigned short* __restrict__ qraw, const float* __restrict__ stq,
    const float* __restrict__ kbuf, const float* __restrict__ vbuf,
    const float* __restrict__ lmask,
    unsigned short* __restrict__ simb, unsigned short* __restrict__ outb,
    float* __restrict__ pmx, float* __restrict__ psm)
{
  __shared__ __align__(16) float qs[128][68];
  __shared__ __align__(16) float ks[64][36];
  __shared__ __align__(16) float vs[64][36];
  __shared__ __align__(16) float ss[128][36];
  __shared__ float sm[64], sr[64], mb[32];
  __shared__ float gm[8][32], gs[8][32];
  int qc = blockIdx.x, q0 = qc * 128, h = blockIdx.y, b = blockIdx.z;
  int bh = b * 8 + h;
  int t = threadIdx.x;
  if (t < 64) {
    sm[t] = stq[(b * 512 + h * 64 + t) * 2];
    sr[t] = stq[(b * 512 + h * 64 + t) * 2 + 1];
  } else if (t < 96) {
    mb[t - 64] = 10000.f * (lmask[b * 32 + (t - 64)] - 1.f);
  }
  for (int e = t; e < 2048; e += 256) {
    int d = e >> 5, n = e & 31;
    ks[d][n] = kbuf[((size_t)b * 512 + h * 64 + d) * 32 + n];
    vs[d][n] = vbuf[((size_t)b * 512 + h * 64 + d) * 32 + n];
  }
  __syncthreads();
  const float scale = 0.04419417382415922f;  // 512^-0.5
  for (int e = t; e < 8192; e += 256) {
    int ql = e >> 6, d = e & 63;
    float v = bf2f(qraw[((size_t)(b * 4096) + q0 + ql) * 512 + h * 64 + d]);
    qs[ql][d] = (v - sm[d]) * sr[d] * scale;
  }
  __syncthreads();
  int ql = t >> 1, half = t & 1, nb = half * 16;
  float acc[16];
#pragma unroll
  for (int i = 0; i < 16; ++i) acc[i] = 0.f;
  for (int d = 0; d < 64; ++d) {
    float qv = qs[ql][d];
    const f32x4* kp = (const f32x4*)&ks[d][nb];
#pragma unroll
    for (int u = 0; u < 4; ++u) {
      f32x4 kv = kp[u];
      acc[u * 4 + 0] += qv * kv[0]; acc[u * 4 + 1] += qv * kv[1];
      acc[u * 4 + 2] += qv * kv[2]; acc[u * 4 + 3] += qv * kv[3];
    }
  }
  unsigned short* sg = simb + (((size_t)bh) * 4096 + q0 + ql) * 32 + nb;
#pragma unroll
  for (int i = 0; i < 16; ++i) {
    float v = acc[i] + mb[nb + i];
    ss[ql][nb + i] = v;
    sg[i] = f2bf(v);
  }
  __syncthreads();
  {
    int n2 = t & 31, rg = t >> 5;
    float pm = -1e30f;
#pragma unroll
    for (int r = 0; r < 16; ++r) pm = fmaxf(pm, ss[rg * 16 + r][n2]);
    float psv = 0.f;
#pragma unroll
    for (int r = 0; r < 16; ++r) psv += __expf(ss[rg * 16 + r][n2] - pm);
    gm[rg][n2] = pm; gs[rg][n2] = psv;
  }
  __syncthreads();
  if (t < 32) {
    float M = gm[0][t], S = gs[0][t];
#pragma unroll
    for (int g = 1; g < 8; ++g) {
      float m2 = gm[g][t], s2 = gs[g][t];
      if (m2 > M) { S = S * __expf(M - m2) + s2; M = m2; }
      else S += s2 * __expf(m2 - M);
    }
    pmx[((size_t)qc * 128 + bh) * 32 + t] = M;
    psm[((size_t)qc * 128 + bh) * 32 + t] = S;
  }
  __syncthreads();
  float xv[16];
  float mx = -1e30f;
#pragma unroll
  for (int i = 0; i < 16; ++i) { xv[i] = ss[ql][nb + i]; mx = fmaxf(mx, xv[i]); }
  mx = fmaxf(mx, __shfl_xor(mx, 1));
  float s = 0.f;
#pragma unroll
  for (int i = 0; i < 16; ++i) { xv[i] = __expf(xv[i] - mx); s += xv[i]; }
  s += __shfl_xor(s, 1);
  float inv = 1.f / s;
#pragma unroll
  for (int i = 0; i < 16; ++i) ss[ql][nb + i] = xv[i] * inv;
  __syncthreads();
  float pr[32];
#pragma unroll
  for (int i = 0; i < 8; ++i) ((f32x4*)pr)[i] = ((const f32x4*)&ss[ql][0])[i];
  unsigned short* op = outb + ((size_t)b * 4096 + q0 + ql) * 512 + h * 64 + half * 32;
#pragma unroll
  for (int d = 0; d < 32; ++d) {
    const float* vr = &vs[half * 32 + d][0];
    float a = 0.f;
#pragma unroll
    for (int n4 = 0; n4 < 8; ++n4) {
      f32x4 v4 = *(const f32x4*)&vr[n4 * 4];
      a += pr[n4 * 4 + 0] * v4[0] + pr[n4 * 4 + 1] * v4[1] +
           pr[n4 * 4 + 2] * v4[2] + pr[n4 * 4 + 3] * v4[3];
    }
    op[d] = f2bf(a);
  }
}

// ---------------- merge latt partial stats ----------------
__global__ __launch_bounds__(256) void latt_merge(const float* __restrict__ pmx,
                                                  const float* __restrict__ psm,
                                                  float* __restrict__ lmx,
                                                  float* __restrict__ lsm)
{
  int i = blockIdx.x * 256 + threadIdx.x;
  int bh = i >> 5, n = i & 31;
  float M = -1e30f, S = 0.f;
#pragma unroll 4
  for (int c = 0; c < 32; ++c) {
    float m2 = pmx[((size_t)c * 128 + bh) * 32 + n];
    float s2 = psm[((size_t)c * 128 + bh) * 32 + n];
    if (m2 > M) { S = S * __expf(M - m2) + s2; M = m2; }
    else S += s2 * __expf(m2 - M);
  }
  lmx[bh * 32 + n] = M;
  lsm[bh * 32 + n] = S;
}

// ---------------- lang_out[b,h,c,n] += sum_q latt[n,q]*lvnorm[c,q] ----------------
__global__ __launch_bounds__(256) void langout_acc_kernel(
    const unsigned short* __restrict__ simb, const float* __restrict__ lmx,
    const float* __restrict__ lsm, const unsigned short* __restrict__ lvraw,
    const float* __restrict__ stlv, float* __restrict__ lacc)
{
  __shared__ __align__(16) float pt[64][32];
  __shared__ __align__(16) float lvt[64][96];
  __shared__ float cm[96], cr[96], lm[32], li[32];
  int bh = blockIdx.x, b = bh >> 3, h = bh & 7;
  int qs0 = blockIdx.y * 512;
  int t = threadIdx.x;
  if (t < 96) { cm[t] = stlv[(b * 768 + h * 96 + t) * 2]; cr[t] = stlv[(b * 768 + h * 96 + t) * 2 + 1]; }
  else if (t >= 128 && t < 160) {
    int n = t - 128;
    lm[n] = lmx[bh * 32 + n];
    li[n] = 1.f / lsm[bh * 32 + n];
  }
  __syncthreads();
  int n = t & 31, cg = t >> 5;
  float acc[12];
#pragma unroll
  for (int r = 0; r < 12; ++r) acc[r] = 0.f;
  for (int c0 = 0; c0 < 512; c0 += 64) {
    if (c0) __syncthreads();
#pragma unroll
    for (int i = 0; i < 8; ++i) {
      int e = t + 256 * i;
      int ql = e >> 5, nn = e & 31;
      float x = bf2f(simb[((size_t)bh * 4096 + qs0 + c0 + ql) * 32 + nn]);
      pt[ql][nn] = __expf(x - lm[nn]) * li[nn];
    }
#pragma unroll
    for (int i = 0; i < 24; ++i) {
      int e = t + 256 * i;
      int ql = e / 96, cc = e % 96;
      float v = bf2f(lvraw[((size_t)(b * 4096) + qs0 + c0 + ql) * 768 + h * 96 + cc]);
      lvt[ql][cc] = (v - cm[cc]) * cr[cc];
    }
    __syncthreads();
    for (int q = 0; q < 64; ++q) {
      float pv = pt[q][n];
      const f32x4* lp = (const f32x4*)&lvt[q][cg * 12];
      f32x4 a0 = lp[0], a1 = lp[1], a2 = lp[2];
      acc[0] += pv * a0[0]; acc[1] += pv * a0[1]; acc[2]  += pv * a0[2]; acc[3]  += pv * a0[3];
      acc[4] += pv * a1[0]; acc[5] += pv * a1[1]; acc[6]  += pv * a1[2]; acc[7]  += pv * a1[3];
      acc[8] += pv * a2[0]; acc[9] += pv * a2[1]; acc[10] += pv * a2[2]; acc[11] += pv * a2[3];
    }
  }
#pragma unroll
  for (int r = 0; r < 12; ++r)
    atomicAdd(&lacc[((size_t)b * 768 + h * 96 + cg * 12 + r) * 32 + n], acc[r]);
}

// ---------------- P = vis * inorm(Wout) ----------------
__global__ __launch_bounds__(256) void prod_kernel(
    const unsigned short* __restrict__ visb, const unsigned short* __restrict__ wraw,
    const float* __restrict__ stw, unsigned short* __restrict__ P)
{
  size_t idx = ((size_t)blockIdx.x * 256 + threadIdx.x) * 8;
  int b = (int)(idx >> 21);
  int c = (int)(idx & 511);
  ushort8 vv = *(const ushort8*)&visb[idx];
  ushort8 wv = *(const ushort8*)&wraw[idx];
  ushort8 pv;
#pragma unroll
  for (int i = 0; i < 8; ++i) {
    float mean = stw[(b * 512 + c + i) * 2], rs = stw[(b * 512 + c + i) * 2 + 1];
    pv[i] = f2bf(bf2f(vv[i]) * ((bf2f(wv[i]) - mean) * rs));
  }
  *(ushort8*)&P[idx] = pv;
}

// ---------------- langW conv + inorm over NL (f32) ----------------
__global__ __launch_bounds__(256) void langW_kernel(
    const float* __restrict__ lacc, const float* __restrict__ w,
    const float* __restrict__ bias, const float* __restrict__ lmask,
    float* __restrict__ lnorm)
{
  int b = blockIdx.x, og = blockIdx.y;
  int ol = threadIdx.x >> 5, n = threadIdx.x & 31;
  int o = og * 8 + ol;
  const float* ab = lacc + (size_t)b * 768 * 32 + n;
  const float* wr = w + (size_t)o * 768;
  float s = 0.f;
#pragma unroll 4
  for (int i = 0; i < 768; ++i) s += wr[i] * ab[(size_t)i * 32];
  float y = s * lmask[b * 32 + n] + bias[o];
  float m = y;
#pragma unroll
  for (int off = 16; off >= 1; off >>= 1) m += __shfl_xor(m, off);
  m *= (1.f / 32.f);
  float d = y - m;
  float vv = d * d;
#pragma unroll
  for (int off = 16; off >= 1; off >>= 1) vv += __shfl_xor(vv, off);
  vv *= (1.f / 32.f);
  lnorm[((size_t)b * 768 + o) * 32 + n] = d * rsqrtf(vv + 1e-5f);
}

__global__ __launch_bounds__(256) void p2_kernel(const float* __restrict__ a,
                                                 const float* __restrict__ b,
                                                 float* __restrict__ o, int n) {
  int i = blockIdx.x * 256 + threadIdx.x;
  if (i < n) o[i] = a[i] * b[i];
}

// ---------------- langmm conv + gelu, store transposed (B,NL,CL) f32 ----------------
__global__ __launch_bounds__(256) void langmm_kernel(
    const float* __restrict__ p2, const float* __restrict__ w,
    const float* __restrict__ bias, float* __restrict__ out1)
{
  int b = blockIdx.x, og = blockIdx.y;
  int ol = threadIdx.x >> 5, n = threadIdx.x & 31;
  int o = og * 8 + ol;
  const float* pb = p2 + (size_t)b * 768 * 32 + n;
  const float* wr = w + (size_t)o * 768;
  float s = 0.f;
#pragma unroll 4
  for (int i = 0; i < 768; ++i) s += wr[i] * pb[(size_t)i * 32];
  s = gelu_f(s + bias[o]);
  __shared__ float tile[8][32];
  tile[ol][n] = s;
  __syncthreads();
  int nn = threadIdx.x >> 3, cl = threadIdx.x & 7;
  out1[((size_t)b * 32 + nn) * 768 + og * 8 + cl] = tile[cl][nn];
}

// ---------------- launch ----------------
extern "C" void kernel_launch(void* const* d_in, const int* in_sizes, int n_in,
                              void* d_out, int out_size, void* d_ws, size_t ws_size,
                              hipStream_t stream)
{
  (void)in_sizes; (void)n_in; (void)out_size; (void)ws_size;
  const float* x       = (const float*)d_in[0];
  const float* l       = (const float*)d_in[1];
  const float* lmask   = (const float*)d_in[2];
  const float* w_vis   = (const float*)d_in[3];
  const float* b_vis   = (const float*)d_in[4];
  const float* w_langp = (const float*)d_in[5];
  const float* b_langp = (const float*)d_in[6];
  const float* w_q     = (const float*)d_in[7];
  const float* b_q     = (const float*)d_in[8];
  const float* w_k     = (const float*)d_in[9];
  const float* b_k     = (const float*)d_in[10];
  const float* w_v     = (const float*)d_in[11];
  const float* b_v     = (const float*)d_in[12];
  const float* w_lv    = (const float*)d_in[13];
  const float* b_lv    = (const float*)d_in[14];
  const float* w_W     = (const float*)d_in[15];
  const float* b_W     = (const float*)d_in[16];
  const float* w_langW = (const float*)d_in[17];
  const float* b_langW = (const float*)d_in[18];
  const float* w_mm    = (const float*)d_in[19];
  const float* b_mm    = (const float*)d_in[20];
  const float* w_langmm= (const float*)d_in[21];
  const float* b_langmm= (const float*)d_in[22];

  char* ws = (char*)d_ws;
  float* srq  = (float*)(ws + OFF_SRQ);
  float* srlv = (float*)(ws + OFF_SRLV);
  float* srw  = (float*)(ws + OFF_SRW);
  float* lacc = (float*)(ws + OFF_LACC);
  float* stq  = (float*)(ws + OFF_STQ);
  float* stlv = (float*)(ws + OFF_STLV);
  float* stw  = (float*)(ws + OFF_STW);
  float* kbuf = (float*)(ws + OFF_KBUF);
  float* vbuf = (float*)(ws + OFF_VBUF);
  float* lang = (float*)(ws + OFF_LANG);
  float* lmx  = (float*)(ws + OFF_LMX);
  float* lsm  = (float*)(ws + OFF_LSM);
  float* lnorm= (float*)(ws + OFF_LNORM);
  float* p2   = (float*)(ws + OFF_P2);
  float* pmx  = (float*)(ws + OFF_PMX);
  float* psm  = (float*)(ws + OFF_PSM);
  unsigned short* wb    = (unsigned short*)(ws + OFF_WB);
  unsigned short* wbvis = wb;
  unsigned short* wbq   = wb + 262144;
  unsigned short* wblv  = wb + 524288;
  unsigned short* wbW   = wb + 917504;
  unsigned short* wbmm  = wb + 1179648;
  unsigned short* qraw  = (unsigned short*)(ws + OFF_Q);
  unsigned short* lvraw = (unsigned short*)(ws + OFF_LV);
  unsigned short* wraw  = (unsigned short*)(ws + OFF_LV);
  unsigned short* simb  = (unsigned short*)(ws + OFF_SIMB);
  float* out0 = (float*)d_out;
  float* out1 = out0 + (size_t)16 * 4096 * 512;
  unsigned short* visb = (unsigned short*)d_out;                 // [0,64MB)
  unsigned short* xb   = (unsigned short*)d_out + 33554432;      // [64,128MB)

  hipMemsetAsync(ws, 0, SZ_ZERO, stream);

  // f32 -> bf16 converts (x + 5 weights)
  cvt_bf16<<<16384, 256, 0, stream>>>(x, xb, 4194304);
  cvt_bf16<<<128, 256, 0, stream>>>(w_vis, wbvis, 32768);
  cvt_bf16<<<128, 256, 0, stream>>>(w_q,   wbq,   32768);
  cvt_bf16<<<192, 256, 0, stream>>>(w_lv,  wblv,  49152);
  cvt_bf16<<<128, 256, 0, stream>>>(w_W,   wbW,   32768);
  cvt_bf16<<<128, 256, 0, stream>>>(w_mm,  wbmm,  32768);

  // language-side small convs (f32)
  sconv<1><<<dim3(16, 96), 256, 0, stream>>>(l, w_langp, b_langp, lmask, lang, 768, 768);
  sconv<0><<<dim3(16, 64), 256, 0, stream>>>(l, w_k, b_k, lmask, kbuf, 512, 768);
  sconv<0><<<dim3(16, 64), 256, 0, stream>>>(l, w_v, b_v, lmask, vbuf, 512, 768);

  // big GEMMs on xb (bf16 A, bf16 W)
  gemm_bt<true,  false, false><<<dim3(512, 4), 256, 0, stream>>>(xb, wbvis, b_vis, visb, nullptr, 512, 512);
  gemm_bt<false, true,  false><<<dim3(512, 4), 256, 0, stream>>>(xb, wbq,   b_q,   qraw,  srq,   512, 512);
  gemm_bt<false, true,  false><<<dim3(512, 6), 256, 0, stream>>>(xb, wblv,  b_lv,  lvraw, srlv,  768, 512);
  finalize_stats<<<32, 256, 0, stream>>>(srq,  stq,  16 * 512, 1.f / 4096.f);
  finalize_stats<<<48, 256, 0, stream>>>(srlv, stlv, 16 * 768, 1.f / 4096.f);

  // attention (fused sim+softmax+PV+latt partials)
  simattv_kernel<<<dim3(32, 8, 16), 256, 0, stream>>>(qraw, stq, kbuf, vbuf, lmask, simb, qraw, pmx, psm);
  latt_merge<<<16, 256, 0, stream>>>(pmx, psm, lmx, lsm);
  langout_acc_kernel<<<dim3(128, 8), 256, 0, stream>>>(simb, lmx, lsm, lvraw, stlv, lacc);

  // visual output path
  gemm_bt<false, true,  false><<<dim3(512, 4), 256, 0, stream>>>(qraw, wbW, b_W, wraw, srw, 512, 512);
  finalize_stats<<<32, 256, 0, stream>>>(srw, stw, 16 * 512, 1.f / 4096.f);
  prod_kernel<<<16384, 256, 0, stream>>>(visb, wraw, stw, qraw);
  gemm_bt<true,  false, true ><<<dim3(512, 4), 256, 0, stream>>>(qraw, wbmm, b_mm, out0, nullptr, 512, 512);

  // language output path
  langW_kernel<<<dim3(16, 96), 256, 0, stream>>>(lacc, w_langW, b_langW, lmask, lnorm);
  p2_kernel<<<1536, 256, 0, stream>>>(lang, lnorm, p2, 16 * 768 * 32);
  langmm_kernel<<<dim3(16, 96), 256, 0, stream>>>(p2, w_langmm, b_langmm, out1);
}